// Round 9
// baseline (271.184 us; speedup 1.0000x reference)
//
#include <hip/hip_runtime.h>
#include <hip/hip_bf16.h>
#include <float.h>

// Problem constants
#define BB    2
#define NSEQ  2048
#define CDIM  1024
#define HH    16
#define DD    64
#define KKEEP 1228

typedef __attribute__((ext_vector_type(8))) short short8_t;
typedef __attribute__((ext_vector_type(4))) short short4_t;
typedef __attribute__((ext_vector_type(4))) float f32x4;
typedef __attribute__((ext_vector_type(4))) float float4_t;
typedef __bf16 bf16x8 __attribute__((ext_vector_type(8)));

static __device__ __forceinline__ short f2bf(float x) {
  __hip_bfloat16 h = __float2bfloat16(x);
  short s;
  __builtin_memcpy(&s, &h, 2);
  return s;
}

static __device__ __forceinline__ float bf2f(short s) {
  unsigned u = ((unsigned)(unsigned short)s) << 16;
  float f;
  __builtin_memcpy(&f, &u, 4);
  return f;
}

static __device__ __forceinline__ f32x4 mfma16(bf16x8 a, bf16x8 b, f32x4 c) {
  return __builtin_amdgcn_mfma_f32_16x16x32_bf16(a, b, c, 0, 0, 0);
}

// ---------------- cast kernels ----------------
__global__ __launch_bounds__(256) void cast_f32_bf16_kernel(
    const float* __restrict__ src, short* __restrict__ dst, int n4) {
  int i = blockIdx.x * 256 + threadIdx.x;
  if (i >= n4) return;
  float4_t v = ((const float4_t*)src)[i];
  short4_t o;
  o[0] = f2bf(v[0]); o[1] = f2bf(v[1]); o[2] = f2bf(v[2]); o[3] = f2bf(v[3]);
  ((short4_t*)dst)[i] = o;
}

// Permute W_qkv rows: dst row rr = c*1024 + h*64 + d  <-  src row h*192 + d*3 + c
__global__ __launch_bounds__(256) void cast_wqkv_kernel(
    const float* __restrict__ w, short* __restrict__ dst) {
  int rr = blockIdx.x;              // 0..3071
  int c = rr >> 10, hd = rr & 1023;
  int h = hd >> 6, d = hd & 63;
  int srow = h * 192 + d * 3 + c;
  int col = threadIdx.x * 4;
  float4_t v = *(const float4_t*)(w + (size_t)srow * CDIM + col);
  short4_t o;
  o[0] = f2bf(v[0]); o[1] = f2bf(v[1]); o[2] = f2bf(v[2]); o[3] = f2bf(v[3]);
  *(short4_t*)(dst + (size_t)rr * CDIM + col) = o;
}

// ---------------- GEMM: C[M,N] = A[M,K] * B[N,K]^T (both bf16, fp32 acc) ----------------
template <int EPI>
__global__ __launch_bounds__(256) void gemm_bt_kernel(
    const short* __restrict__ A, const short* __restrict__ B, int K, int N,
    float* __restrict__ outF, short* __restrict__ outQ,
    short* __restrict__ outK, short* __restrict__ outV) {
  __shared__ short lA[128 * 32];
  __shared__ short lB[128 * 32];
  int m0 = blockIdx.y * 128, n0 = blockIdx.x * 128;
  int tid = threadIdx.x, lane = tid & 63;
  int w = tid >> 6;
  int lq = lane & 15, lg = lane >> 4;
  int wm = w >> 1, wn = w & 1;

  f32x4 acc[4][4];
#pragma unroll
  for (int m = 0; m < 4; ++m)
#pragma unroll
    for (int n = 0; n < 4; ++n) acc[m][n] = (f32x4){0.f, 0.f, 0.f, 0.f};

  const int c0 = tid, c1 = tid + 256;
  for (int k0 = 0; k0 < K; k0 += 32) {
    short8_t a0 = *(const short8_t*)(A + (size_t)(m0 + (c0 >> 2)) * K + k0 + (c0 & 3) * 8);
    short8_t a1 = *(const short8_t*)(A + (size_t)(m0 + (c1 >> 2)) * K + k0 + (c1 & 3) * 8);
    short8_t b0 = *(const short8_t*)(B + (size_t)(n0 + (c0 >> 2)) * K + k0 + (c0 & 3) * 8);
    short8_t b1 = *(const short8_t*)(B + (size_t)(n0 + (c1 >> 2)) * K + k0 + (c1 & 3) * 8);
    *(short8_t*)(lA + c0 * 8) = a0;
    *(short8_t*)(lA + c1 * 8) = a1;
    *(short8_t*)(lB + c0 * 8) = b0;
    *(short8_t*)(lB + c1 * 8) = b1;
    __syncthreads();
    bf16x8 af[4], bf[4];
#pragma unroll
    for (int m = 0; m < 4; ++m)
      af[m] = *(const bf16x8*)(lA + (wm * 64 + m * 16 + lq) * 32 + lg * 8);
#pragma unroll
    for (int n = 0; n < 4; ++n)
      bf[n] = *(const bf16x8*)(lB + (wn * 64 + n * 16 + lq) * 32 + lg * 8);
#pragma unroll
    for (int m = 0; m < 4; ++m)
#pragma unroll
      for (int n = 0; n < 4; ++n) acc[m][n] = mfma16(af[m], bf[n], acc[m][n]);
    __syncthreads();
  }

#pragma unroll
  for (int m = 0; m < 4; ++m)
#pragma unroll
    for (int n = 0; n < 4; ++n) {
      int row_b = m0 + wm * 64 + m * 16 + lg * 4;
      int col = n0 + wn * 64 + n * 16 + lq;
#pragma unroll
      for (int r = 0; r < 4; ++r) {
        float v = acc[m][n][r];
        int row = row_b + r;
        if constexpr (EPI == 1) {
          outF[(size_t)row * N + col] = v;
        } else {
          int c = col >> 10, cc = col & 1023;
          int bb2 = row >> 11, nn = row & 2047;
          int hh2 = cc >> 6, dd2 = cc & 63;
          short val = f2bf(v);
          if (c == 0)
            outQ[((size_t)(bb2 * HH + hh2) * NSEQ + nn) * DD + dd2] = val;
          else if (c == 1)
            outK[((size_t)(bb2 * HH + hh2) * NSEQ + nn) * DD + dd2] = val;
          else
            outV[((size_t)(bb2 * HH + hh2) * DD + dd2) * NSEQ + nn] = val;
        }
      }
    }
}

// ---------------- top-k selection -> keep bitmap + jmin (stable: value desc, index asc) ----
__global__ __launch_bounds__(256) void topk_kernel(const int* __restrict__ seq_mask,
                                                   unsigned* __restrict__ keepw,
                                                   int* __restrict__ jminb) {
  __shared__ int hist[10];
  __shared__ int vals[NSEQ];
  __shared__ int seqc[256];
  __shared__ unsigned wbuf[64];
  __shared__ int sT, sNeed, sMin;
  int bh = blockIdx.x, tid = threadIdx.x;
  if (tid < 10) hist[tid] = 0;
  if (tid < 64) wbuf[tid] = 0;
  if (tid == 0) sMin = NSEQ;
  __syncthreads();
  const int* sm = seq_mask + (size_t)bh * NSEQ;
  for (int i = tid; i < NSEQ; i += 256) {
    int v = sm[i];
    vals[i] = v;
    atomicAdd(&hist[v], 1);
  }
  __syncthreads();
  if (tid == 0) {
    int cum = 0, t = 0;
    for (int v = 9; v >= 0; --v) {
      int hv = hist[v];
      if (cum + hv >= KKEEP) { t = v; break; }
      cum += hv;
    }
    sT = t;
    sNeed = KKEEP - cum;   // ties (value==t) kept, lowest indices first
  }
  __syncthreads();
  int t = sT, need = sNeed;
  int base = tid * 8, leq = 0;
  int lv[8];
#pragma unroll
  for (int j = 0; j < 8; ++j) {
    lv[j] = vals[base + j];
    leq += (lv[j] == t);
  }
  seqc[tid] = leq;
  __syncthreads();
  for (int off = 1; off < 256; off <<= 1) {
    int a = 0;
    if (tid >= off) a = seqc[tid - off];
    __syncthreads();
    seqc[tid] += a;
    __syncthreads();
  }
  int eqp = seqc[tid] - leq;  // exclusive prefix of (v==t)
  unsigned mybits = 0;
#pragma unroll
  for (int j = 0; j < 8; ++j) {
    int v = lv[j];
    bool kept = (v > t) || (v == t && eqp < need);
    if (v == t) eqp++;
    if (kept) mybits |= (1u << j);
  }
  atomicOr(&wbuf[tid >> 2], mybits << ((tid & 3) * 8));
  if (mybits) atomicMin(&sMin, base + __ffs(mybits) - 1);
  __syncthreads();
  if (tid < 64) keepw[(size_t)bh * 64 + tid] = wbuf[tid];
  if (tid == 0) jminb[bh] = sMin;
}

// ---------------- flash attention, key-split, BOTH BATCHES PER WAVE ----------------
// Work item = one wave = (h, 16-row tile, key-part), processing b=0 AND b=1
// (they share the pos_bias row -> pb loaded once, used twice; pb HBM halves).
// Tiles 64..127 and tile 0 are "big" (2 key-halves -> partials + combine);
// tiles 1..63 "small" (direct write). Heavy-first ordering.
#define PBLOAD(SUF, T)                                                         \
  do {                                                                         \
    int kb0_ = (T) * 32;                                                       \
    pb0##SUF = *(const float4_t*)(pbrow + kb0_ + lg * 4);                      \
    pb1##SUF = *(const float4_t*)(pbrow + kb0_ + 16 + lg * 4);                 \
    kw0##SUF = kwp0[T];                                                        \
    kw1##SUF = kwp1[T];                                                        \
  } while (0)

// scores -> skip-rescale softmax -> P pack -> PV, for one batch.
#define SCORE_SM_PV(S0, S1, KW, MR, LS, O0, O1, O2, O3, MYP, PB0, PB1, V0, V1, V2, V3) \
  do {                                                                         \
    float cm = -FLT_MAX;                                                       \
    float sv[8];                                                               \
    unsigned vb = 0;                                                           \
    _Pragma("unroll") for (int r = 0; r < 4; ++r) {                            \
      int j0_ = kb0c + lg * 4 + r;                                             \
      unsigned keep0 = ((KW) >> (lg * 4 + r)) & 1u;                            \
      float x0 = (keep0 && j0_ <= qglob) ? fmaf((S0)[r], 0.125f, (PB0)[r])     \
                                         : -FLT_MAX;                           \
      vb |= keep0 << r;                                                        \
      sv[r] = x0;                                                              \
      cm = fmaxf(cm, x0);                                                      \
      unsigned keep1 = ((KW) >> (16 + lg * 4 + r)) & 1u;                       \
      float x1 = (keep1 && j0_ + 16 <= qglob)                                  \
                     ? fmaf((S1)[r], 0.125f, (PB1)[r])                         \
                     : -FLT_MAX;                                               \
      vb |= keep1 << (4 + r);                                                  \
      sv[4 + r] = x1;                                                          \
      cm = fmaxf(cm, x1);                                                      \
    }                                                                          \
    if (__any(cm > (MR))) {                                                    \
      float rm = fmaxf(cm, __shfl_xor(cm, 16));                                \
      rm = fmaxf(rm, __shfl_xor(rm, 32));                                      \
      float mnew = fmaxf((MR), rm);                                            \
      float fsc = __expf((MR) - mnew);                                         \
      (MR) = mnew;                                                             \
      (LS) *= fsc;                                                             \
      float f0 = __shfl(fsc, lg * 4 + 0);                                      \
      float f1 = __shfl(fsc, lg * 4 + 1);                                      \
      float f2 = __shfl(fsc, lg * 4 + 2);                                      \
      float f3 = __shfl(fsc, lg * 4 + 3);                                      \
      (O0)[0] *= f0; (O0)[1] *= f1; (O0)[2] *= f2; (O0)[3] *= f3;              \
      (O1)[0] *= f0; (O1)[1] *= f1; (O1)[2] *= f2; (O1)[3] *= f3;              \
      (O2)[0] *= f0; (O2)[1] *= f1; (O2)[2] *= f2; (O2)[3] *= f3;              \
      (O3)[0] *= f0; (O3)[1] *= f1; (O3)[2] *= f2; (O3)[3] *= f3;              \
    }                                                                          \
    float psum = 0.f;                                                          \
    short4_t pw0, pw1;                                                         \
    _Pragma("unroll") for (int j2 = 0; j2 < 4; ++j2) {                         \
      float pv = ((vb >> j2) & 1u) ? __expf(sv[j2] - (MR)) : 0.f;              \
      psum += pv;                                                              \
      pw0[j2] = f2bf(pv);                                                      \
    }                                                                          \
    _Pragma("unroll") for (int j2 = 0; j2 < 4; ++j2) {                         \
      float pv = ((vb >> (4 + j2)) & 1u) ? __expf(sv[4 + j2] - (MR)) : 0.f;    \
      psum += pv;                                                              \
      pw1[j2] = f2bf(pv);                                                      \
    }                                                                          \
    (LS) += psum;                                                              \
    *(short4_t*)((MYP) + lq * 72 + lg * 8) = pw0;                              \
    *(short4_t*)((MYP) + lq * 72 + 32 + lg * 8) = pw1;                         \
    bf16x8 pa = *(const bf16x8*)((MYP) + lq * 72 + lg * 16);                   \
    (O0) = mfma16(pa, (V0), (O0));                                             \
    (O1) = mfma16(pa, (V1), (O1));                                             \
    (O2) = mfma16(pa, (V2), (O2));                                             \
    (O3) = mfma16(pa, (V3), (O3));                                             \
  } while (0)

// One chunk, both batches. vmcnt-order: Kb0,Vb0 | QK b0 | Kb1,Vb1,pb(next) |
// b0 tail (V-wait leaves Kb1/Vb1/pbnext) | QK b1 (Kb1 covered by b0 tail) |
// b1 tail (V-wait leaves pbnext in flight into next chunk).
#define CHUNK2(SUF, OSUF, T)                                                   \
  do {                                                                         \
    int kb0c = (T) * 32;                                                       \
    const short* kp0_ = kb_bh0 + (size_t)(kb0c + lq) * DD + lg * 8;            \
    bf16x8 a00 = *(const bf16x8*)kp0_;                                         \
    bf16x8 a01 = *(const bf16x8*)(kp0_ + 32);                                  \
    bf16x8 a02 = *(const bf16x8*)(kp0_ + 16 * DD);                             \
    bf16x8 a03 = *(const bf16x8*)(kp0_ + 16 * DD + 32);                        \
    const short* vp0_ = vT_bh0 + kb0c + lg * 8;                                \
    bf16x8 v00 = *(const bf16x8*)(vp0_);                                       \
    bf16x8 v01 = *(const bf16x8*)(vp0_ + 16 * NSEQ);                           \
    bf16x8 v02 = *(const bf16x8*)(vp0_ + 32 * NSEQ);                           \
    bf16x8 v03 = *(const bf16x8*)(vp0_ + 48 * NSEQ);                           \
    f32x4 s00 = (f32x4){0.f, 0.f, 0.f, 0.f};                                   \
    s00 = mfma16(a00, qf00, s00);                                              \
    s00 = mfma16(a01, qf01, s00);                                              \
    f32x4 s01 = (f32x4){0.f, 0.f, 0.f, 0.f};                                   \
    s01 = mfma16(a02, qf00, s01);                                              \
    s01 = mfma16(a03, qf01, s01);                                              \
    const short* kp1_ = kb_bh1 + (size_t)(kb0c + lq) * DD + lg * 8;            \
    bf16x8 a10 = *(const bf16x8*)kp1_;                                         \
    bf16x8 a11 = *(const bf16x8*)(kp1_ + 32);                                  \
    bf16x8 a12 = *(const bf16x8*)(kp1_ + 16 * DD);                             \
    bf16x8 a13 = *(const bf16x8*)(kp1_ + 16 * DD + 32);                        \
    const short* vp1_ = vT_bh1 + kb0c + lg * 8;                                \
    bf16x8 v10 = *(const bf16x8*)(vp1_);                                       \
    bf16x8 v11 = *(const bf16x8*)(vp1_ + 16 * NSEQ);                           \
    bf16x8 v12 = *(const bf16x8*)(vp1_ + 32 * NSEQ);                           \
    bf16x8 v13 = *(const bf16x8*)(vp1_ + 48 * NSEQ);                           \
    if ((T) + 1 < t1) PBLOAD(OSUF, (T) + 1);                                   \
    SCORE_SM_PV(s00, s01, kw0##SUF, mrun0, lsum0, o00, o01, o02, o03, myp0,    \
                pb0##SUF, pb1##SUF, v00, v01, v02, v03);                       \
    f32x4 s10 = (f32x4){0.f, 0.f, 0.f, 0.f};                                   \
    s10 = mfma16(a10, qf10, s10);                                              \
    s10 = mfma16(a11, qf11, s10);                                              \
    f32x4 s11 = (f32x4){0.f, 0.f, 0.f, 0.f};                                   \
    s11 = mfma16(a12, qf10, s11);                                              \
    s11 = mfma16(a13, qf11, s11);                                              \
    SCORE_SM_PV(s10, s11, kw1##SUF, mrun1, lsum1, o10, o11, o12, o13, myp1,    \
                pb0##SUF, pb1##SUF, v10, v11, v12, v13);                       \
  } while (0)

__global__ __launch_bounds__(128) void attn_split_kernel(
    const short* __restrict__ qb, const short* __restrict__ kb,
    const short* __restrict__ vT, const unsigned* __restrict__ keepw,
    const int* __restrict__ jminb, const float* __restrict__ pos_bias,
    short* __restrict__ Opart, float* __restrict__ mlb,
    short* __restrict__ attn_out) {
  __shared__ short pls[2][2][16][36];   // [wave][batch] P bounce, 72B rows
  int w = threadIdx.x >> 6, lane = threadIdx.x & 63;
  int lq = lane & 15, lg = lane >> 4;
  int gid = blockIdx.x * 2 + w;      // 0..3087

  int h, tile, part;
  if (gid < 2080) {                  // big halves, heavy-first
    h = gid & 15;
    int rem = gid >> 4;              // 0..129
    int trank = rem >> 1;            // 0..64
    tile = (trank < 64) ? (127 - trank) : 0;
    part = rem & 1;
  } else {                           // small tiles, descending 63..1
    int g2 = gid - 2080;
    h = g2 & 15;
    tile = 63 - (g2 >> 4);
    part = 0;
  }
  int bh0 = h, bh1 = HH + h;
  int q0 = tile << 4;
  int qglob = q0 + lq;

  int jmin0 = jminb[bh0], jmin1 = jminb[bh1];
  int bound = (q0 < jmin0 || q0 < jmin1) ? NSEQ : (q0 + 16);
  int nkb = (bound + 31) >> 5;
  int t0 = 0, t1 = nkb;
  bool big = (tile >= 64) || (tile == 0);
  if (big) {
    int half = nkb >> 1;
    if (part) t0 = half; else t1 = half;
  }

  const short* qp0 = qb + ((size_t)bh0 * NSEQ + qglob) * DD;
  bf16x8 qf00 = *(const bf16x8*)(qp0 + lg * 8);
  bf16x8 qf01 = *(const bf16x8*)(qp0 + 32 + lg * 8);
  const short* qp1 = qb + ((size_t)bh1 * NSEQ + qglob) * DD;
  bf16x8 qf10 = *(const bf16x8*)(qp1 + lg * 8);
  bf16x8 qf11 = *(const bf16x8*)(qp1 + 32 + lg * 8);

  const short* kb_bh0 = kb + (size_t)bh0 * NSEQ * DD;
  const short* kb_bh1 = kb + (size_t)bh1 * NSEQ * DD;
  const short* vT_bh0 = vT + ((size_t)bh0 * DD + lq) * NSEQ;
  const short* vT_bh1 = vT + ((size_t)bh1 * DD + lq) * NSEQ;
  const float* pbrow = pos_bias + ((size_t)h * NSEQ + qglob) * NSEQ;
  const unsigned* kwp0 = keepw + (size_t)bh0 * 64;
  const unsigned* kwp1 = keepw + (size_t)bh1 * 64;
  char* myp0 = (char*)&pls[w][0][0][0];
  char* myp1 = (char*)&pls[w][1][0][0];

  float mrun0 = -FLT_MAX, lsum0 = 0.f, mrun1 = -FLT_MAX, lsum1 = 0.f;
  f32x4 o00 = (f32x4){0.f, 0.f, 0.f, 0.f}, o01 = o00, o02 = o00, o03 = o00;
  f32x4 o10 = o00, o11 = o00, o12 = o00, o13 = o00;

  float4_t pb0A, pb1A, pb0B, pb1B;
  unsigned kw0A, kw1A, kw0B, kw1B;

  if (t0 < t1) {
    PBLOAD(A, t0);
    int t = t0;
    for (;;) {
      CHUNK2(A, B, t);
      if (++t >= t1) break;
      CHUNK2(B, A, t);
      if (++t >= t1) break;
    }
  }

  if (big) {
    int t65 = (tile >= 64) ? (tile - 64) : 64;
    {  // batch 0 partial
      float lrow = lsum0;
      lrow += __shfl_xor(lrow, 16);
      lrow += __shfl_xor(lrow, 32);
      int pidx = ((bh0 * 65 + t65) << 1) + part;
      if (lg == 0) {
        mlb[pidx * 32 + lq] = mrun0;
        mlb[pidx * 32 + 16 + lq] = lrow;
      }
      short* op = Opart + (size_t)pidx * 1024;
#pragma unroll
      for (int rr = 0; rr < 4; ++rr) {
        int row = lg * 4 + rr;
        op[row * 64 + lq]      = f2bf(o00[rr]);
        op[row * 64 + lq + 16] = f2bf(o01[rr]);
        op[row * 64 + lq + 32] = f2bf(o02[rr]);
        op[row * 64 + lq + 48] = f2bf(o03[rr]);
      }
    }
    {  // batch 1 partial
      float lrow = lsum1;
      lrow += __shfl_xor(lrow, 16);
      lrow += __shfl_xor(lrow, 32);
      int pidx = ((bh1 * 65 + t65) << 1) + part;
      if (lg == 0) {
        mlb[pidx * 32 + lq] = mrun1;
        mlb[pidx * 32 + 16 + lq] = lrow;
      }
      short* op = Opart + (size_t)pidx * 1024;
#pragma unroll
      for (int rr = 0; rr < 4; ++rr) {
        int row = lg * 4 + rr;
        op[row * 64 + lq]      = f2bf(o10[rr]);
        op[row * 64 + lq + 16] = f2bf(o11[rr]);
        op[row * 64 + lq + 32] = f2bf(o12[rr]);
        op[row * 64 + lq + 48] = f2bf(o13[rr]);
      }
    }
  } else {
    {  // batch 0 direct
      float ltot = lsum0;
      ltot += __shfl_xor(ltot, 16);
      ltot += __shfl_xor(ltot, 32);
      float inv = 1.f / ltot;
      float i0 = __shfl(inv, lg * 4 + 0);
      float i1 = __shfl(inv, lg * 4 + 1);
      float i2 = __shfl(inv, lg * 4 + 2);
      float i3 = __shfl(inv, lg * 4 + 3);
      short* ob = attn_out + ((size_t)q0 + lg * 4) * CDIM + h * DD + lq;
#pragma unroll
      for (int rr = 0; rr < 4; ++rr) {
        float ir = (rr == 0) ? i0 : (rr == 1) ? i1 : (rr == 2) ? i2 : i3;
        short* orow = ob + (size_t)rr * CDIM;
        orow[0]  = f2bf(o00[rr] * ir);
        orow[16] = f2bf(o01[rr] * ir);
        orow[32] = f2bf(o02[rr] * ir);
        orow[48] = f2bf(o03[rr] * ir);
      }
    }
    {  // batch 1 direct
      float ltot = lsum1;
      ltot += __shfl_xor(ltot, 16);
      ltot += __shfl_xor(ltot, 32);
      float inv = 1.f / ltot;
      float i0 = __shfl(inv, lg * 4 + 0);
      float i1 = __shfl(inv, lg * 4 + 1);
      float i2 = __shfl(inv, lg * 4 + 2);
      float i3 = __shfl(inv, lg * 4 + 3);
      short* ob = attn_out + ((size_t)NSEQ + q0 + lg * 4) * CDIM + h * DD + lq;
#pragma unroll
      for (int rr = 0; rr < 4; ++rr) {
        float ir = (rr == 0) ? i0 : (rr == 1) ? i1 : (rr == 2) ? i2 : i3;
        short* orow = ob + (size_t)rr * CDIM;
        orow[0]  = f2bf(o10[rr] * ir);
        orow[16] = f2bf(o11[rr] * ir);
        orow[32] = f2bf(o12[rr] * ir);
        orow[48] = f2bf(o13[rr] * ir);
      }
    }
  }
}

// ---------------- combine partials for big tiles ----------------
__global__ __launch_bounds__(64) void combine_kernel(
    const float* __restrict__ mlb, const short* __restrict__ Opart,
    short* __restrict__ attn_out) {
  int blk = blockIdx.x;              // 0..2079
  int bh = blk & 31, t65 = blk >> 5; // t65 0..64
  int tile = (t65 < 64) ? (64 + t65) : 0;
  int b = bh >> 4, h = bh & 15;
  int lane = threadIdx.x;
  int row = lane >> 2, c0 = (lane & 3) * 16;
  int p0 = (bh * 65 + t65) << 1, p1 = p0 + 1;
  float m0 = mlb[p0 * 32 + row], l0 = mlb[p0 * 32 + 16 + row];
  float m1 = mlb[p1 * 32 + row], l1 = mlb[p1 * 32 + 16 + row];
  float M = fmaxf(m0, m1);
  float f0 = __expf(m0 - M), f1 = __expf(m1 - M);
  float L = l0 * f0 + l1 * f1;
  float inv = 1.f / L;
  const short* q0p = Opart + (size_t)p0 * 1024 + row * 64 + c0;
  const short* q1p = Opart + (size_t)p1 * 1024 + row * 64 + c0;
  short8_t x0a = *(const short8_t*)q0p;
  short8_t x0b = *(const short8_t*)(q0p + 8);
  short8_t x1a = *(const short8_t*)q1p;
  short8_t x1b = *(const short8_t*)(q1p + 8);
  short* orow = attn_out + ((size_t)b * NSEQ + tile * 16 + row) * CDIM + h * DD + c0;
  short8_t oa, ob;
#pragma unroll
  for (int jj = 0; jj < 8; ++jj) {
    float a = bf2f(x0a[jj]) * f0 + bf2f(x1a[jj]) * f1;
    oa[jj] = f2bf(a * inv);
  }
#pragma unroll
  for (int jj = 0; jj < 8; ++jj) {
    float a = bf2f(x0b[jj]) * f0 + bf2f(x1b[jj]) * f1;
    ob[jj] = f2bf(a * inv);
  }
  *(short8_t*)orow = oa;
  *(short8_t*)(orow + 8) = ob;
}

// ---------------- launch ----------------
extern "C" void kernel_launch(void* const* d_in, const int* in_sizes, int n_in,
                              void* d_out, int out_size, void* d_ws, size_t ws_size,
                              hipStream_t stream) {
  const float* x        = (const float*)d_in[0];
  const float* Wqkv     = (const float*)d_in[1];
  const float* Wout     = (const float*)d_in[2];
  const float* pos_bias = (const float*)d_in[3];
  const int*   seq_mask = (const int*)d_in[4];
  float* out = (float*)d_out;

  char* ws = (char*)d_ws;
  short* xb    = (short*)(ws);                          // 8 MB  x bf16 (dead after GEMM0)
  short* wqkvb = (short*)(ws + ((size_t)8  << 20));     // 6 MB  W_qkv bf16 (dead after GEMM0)
  short* woutb = (short*)(ws + ((size_t)14 << 20));     // 2 MB  W_out bf16
  short* qb    = (short*)(ws + ((size_t)16 << 20));     // 8 MB  q bf16 [B,H,N,D]
  short* kbuf  = (short*)(ws + ((size_t)24 << 20));     // 8 MB  k bf16 [B,H,N,D]
  short* vTb   = (short*)(ws + ((size_t)32 << 20));     // 8 MB  vT bf16 [B,H,D,N]
  unsigned* keepw = (unsigned*)(ws + ((size_t)40 << 20)); // 8 KB keep bitmap [BH,64]
  int* jminb   = (int*)(ws + ((size_t)40 << 20) + 65536); // 128 B jmin [BH]
  short* aob   = (short*)(ws + ((size_t)41 << 20));     // 8 MB  attn_out bf16
  // partials overlay xb/wqkvb (temporally disjoint: written by attn, after GEMM0)
  short* Opart = (short*)(ws);                          // 4160 * 1024 shorts = 8.125 MB
  float* mlb   = (float*)(ws + ((size_t)17 << 19));     // at 8.5 MB, 4160*128B

  cast_f32_bf16_kernel<<<4096, 256, 0, stream>>>(x, xb, (BB * NSEQ * CDIM) / 4);
  cast_wqkv_kernel<<<3072, 256, 0, stream>>>(Wqkv, wqkvb);
  cast_f32_bf16_kernel<<<1024, 256, 0, stream>>>(Wout, woutb, (CDIM * HH * DD) / 4);

  gemm_bt_kernel<0><<<dim3(24, 32), 256, 0, stream>>>(xb, wqkvb, CDIM, 3 * HH * DD,
                                                      nullptr, qb, kbuf, vTb);

  topk_kernel<<<BB * HH, 256, 0, stream>>>(seq_mask, keepw, jminb);

  attn_split_kernel<<<1544, 128, 0, stream>>>(qb, kbuf, vTb, keepw, jminb,
                                              pos_bias, Opart, mlb, aob);

  combine_kernel<<<2080, 64, 0, stream>>>(mlb, Opart, aob);

  gemm_bt_kernel<1><<<dim3(8, 32), 256, 0, stream>>>(aob, woutb, HH * DD, CDIM,
                                                     out, nullptr, nullptr, nullptr);
}

// Round 10
// 208.242 us; speedup vs baseline: 1.3023x; 1.3023x over previous
//
#include <hip/hip_runtime.h>
#include <hip/hip_bf16.h>
#include <float.h>

// Problem constants
#define BB    2
#define NSEQ  2048
#define CDIM  1024
#define HH    16
#define DD    64
#define KKEEP 1228

typedef __attribute__((ext_vector_type(8))) short short8_t;
typedef __attribute__((ext_vector_type(4))) short short4_t;
typedef __attribute__((ext_vector_type(4))) float f32x4;
typedef __attribute__((ext_vector_type(16))) float f32x16;
typedef __attribute__((ext_vector_type(4))) float float4_t;
typedef __attribute__((ext_vector_type(4))) unsigned uint4_t;
typedef __bf16 bf16x8 __attribute__((ext_vector_type(8)));

#define Z16 ((f32x16){0.f,0.f,0.f,0.f,0.f,0.f,0.f,0.f,0.f,0.f,0.f,0.f,0.f,0.f,0.f,0.f})

static __device__ __forceinline__ short f2bf(float x) {
  __hip_bfloat16 h = __float2bfloat16(x);
  short s;
  __builtin_memcpy(&s, &h, 2);
  return s;
}

static __device__ __forceinline__ float bf2f(short s) {
  unsigned u = ((unsigned)(unsigned short)s) << 16;
  float f;
  __builtin_memcpy(&f, &u, 4);
  return f;
}

static __device__ __forceinline__ f32x4 mfma16(bf16x8 a, bf16x8 b, f32x4 c) {
  return __builtin_amdgcn_mfma_f32_16x16x32_bf16(a, b, c, 0, 0, 0);
}

static __device__ __forceinline__ f32x16 mfma32(bf16x8 a, bf16x8 b, f32x16 c) {
  return __builtin_amdgcn_mfma_f32_32x32x16_bf16(a, b, c, 0, 0, 0);
}

// ---------------- cast kernels ----------------
__global__ __launch_bounds__(256) void cast_f32_bf16_kernel(
    const float* __restrict__ src, short* __restrict__ dst, int n4) {
  int i = blockIdx.x * 256 + threadIdx.x;
  if (i >= n4) return;
  float4_t v = ((const float4_t*)src)[i];
  short4_t o;
  o[0] = f2bf(v[0]); o[1] = f2bf(v[1]); o[2] = f2bf(v[2]); o[3] = f2bf(v[3]);
  ((short4_t*)dst)[i] = o;
}

// Permute W_qkv rows: dst row rr = c*1024 + h*64 + d  <-  src row h*192 + d*3 + c
__global__ __launch_bounds__(256) void cast_wqkv_kernel(
    const float* __restrict__ w, short* __restrict__ dst) {
  int rr = blockIdx.x;              // 0..3071
  int c = rr >> 10, hd = rr & 1023;
  int h = hd >> 6, d = hd & 63;
  int srow = h * 192 + d * 3 + c;
  int col = threadIdx.x * 4;
  float4_t v = *(const float4_t*)(w + (size_t)srow * CDIM + col);
  short4_t o;
  o[0] = f2bf(v[0]); o[1] = f2bf(v[1]); o[2] = f2bf(v[2]); o[3] = f2bf(v[3]);
  *(short4_t*)(dst + (size_t)rr * CDIM + col) = o;
}

// ---------------- GEMM: C[M,N] = A[M,K] * B[N,K]^T (both bf16, fp32 acc) ----------------
template <int EPI>
__global__ __launch_bounds__(256) void gemm_bt_kernel(
    const short* __restrict__ A, const short* __restrict__ B, int K, int N,
    float* __restrict__ outF, short* __restrict__ outQ,
    short* __restrict__ outK, short* __restrict__ outV) {
  __shared__ short lA[128 * 32];
  __shared__ short lB[128 * 32];
  int m0 = blockIdx.y * 128, n0 = blockIdx.x * 128;
  int tid = threadIdx.x, lane = tid & 63;
  int w = tid >> 6;
  int lq = lane & 15, lg = lane >> 4;
  int wm = w >> 1, wn = w & 1;

  f32x4 acc[4][4];
#pragma unroll
  for (int m = 0; m < 4; ++m)
#pragma unroll
    for (int n = 0; n < 4; ++n) acc[m][n] = (f32x4){0.f, 0.f, 0.f, 0.f};

  const int c0 = tid, c1 = tid + 256;
  for (int k0 = 0; k0 < K; k0 += 32) {
    short8_t a0 = *(const short8_t*)(A + (size_t)(m0 + (c0 >> 2)) * K + k0 + (c0 & 3) * 8);
    short8_t a1 = *(const short8_t*)(A + (size_t)(m0 + (c1 >> 2)) * K + k0 + (c1 & 3) * 8);
    short8_t b0 = *(const short8_t*)(B + (size_t)(n0 + (c0 >> 2)) * K + k0 + (c0 & 3) * 8);
    short8_t b1 = *(const short8_t*)(B + (size_t)(n0 + (c1 >> 2)) * K + k0 + (c1 & 3) * 8);
    *(short8_t*)(lA + c0 * 8) = a0;
    *(short8_t*)(lA + c1 * 8) = a1;
    *(short8_t*)(lB + c0 * 8) = b0;
    *(short8_t*)(lB + c1 * 8) = b1;
    __syncthreads();
    bf16x8 af[4], bf[4];
#pragma unroll
    for (int m = 0; m < 4; ++m)
      af[m] = *(const bf16x8*)(lA + (wm * 64 + m * 16 + lq) * 32 + lg * 8);
#pragma unroll
    for (int n = 0; n < 4; ++n)
      bf[n] = *(const bf16x8*)(lB + (wn * 64 + n * 16 + lq) * 32 + lg * 8);
#pragma unroll
    for (int m = 0; m < 4; ++m)
#pragma unroll
      for (int n = 0; n < 4; ++n) acc[m][n] = mfma16(af[m], bf[n], acc[m][n]);
    __syncthreads();
  }

#pragma unroll
  for (int m = 0; m < 4; ++m)
#pragma unroll
    for (int n = 0; n < 4; ++n) {
      int row_b = m0 + wm * 64 + m * 16 + lg * 4;
      int col = n0 + wn * 64 + n * 16 + lq;
#pragma unroll
      for (int r = 0; r < 4; ++r) {
        float v = acc[m][n][r];
        int row = row_b + r;
        if constexpr (EPI == 1) {
          outF[(size_t)row * N + col] = v;
        } else {
          int c = col >> 10, cc = col & 1023;
          int bb2 = row >> 11, nn = row & 2047;
          int hh2 = cc >> 6, dd2 = cc & 63;
          short val = f2bf(v);
          if (c == 0)
            outQ[((size_t)(bb2 * HH + hh2) * NSEQ + nn) * DD + dd2] = val;
          else if (c == 1)
            outK[((size_t)(bb2 * HH + hh2) * NSEQ + nn) * DD + dd2] = val;
          else
            outV[((size_t)(bb2 * HH + hh2) * DD + dd2) * NSEQ + nn] = val;
        }
      }
    }
}

// ---------------- top-k selection -> keep bitmap + jmin (stable: value desc, index asc) ----
__global__ __launch_bounds__(256) void topk_kernel(const int* __restrict__ seq_mask,
                                                   unsigned* __restrict__ keepw,
                                                   int* __restrict__ jminb) {
  __shared__ int hist[10];
  __shared__ int vals[NSEQ];
  __shared__ int seqc[256];
  __shared__ unsigned wbuf[64];
  __shared__ int sT, sNeed, sMin;
  int bh = blockIdx.x, tid = threadIdx.x;
  if (tid < 10) hist[tid] = 0;
  if (tid < 64) wbuf[tid] = 0;
  if (tid == 0) sMin = NSEQ;
  __syncthreads();
  const int* sm = seq_mask + (size_t)bh * NSEQ;
  for (int i = tid; i < NSEQ; i += 256) {
    int v = sm[i];
    vals[i] = v;
    atomicAdd(&hist[v], 1);
  }
  __syncthreads();
  if (tid == 0) {
    int cum = 0, t = 0;
    for (int v = 9; v >= 0; --v) {
      int hv = hist[v];
      if (cum + hv >= KKEEP) { t = v; break; }
      cum += hv;
    }
    sT = t;
    sNeed = KKEEP - cum;   // ties (value==t) kept, lowest indices first
  }
  __syncthreads();
  int t = sT, need = sNeed;
  int base = tid * 8, leq = 0;
  int lv[8];
#pragma unroll
  for (int j = 0; j < 8; ++j) {
    lv[j] = vals[base + j];
    leq += (lv[j] == t);
  }
  seqc[tid] = leq;
  __syncthreads();
  for (int off = 1; off < 256; off <<= 1) {
    int a = 0;
    if (tid >= off) a = seqc[tid - off];
    __syncthreads();
    seqc[tid] += a;
    __syncthreads();
  }
  int eqp = seqc[tid] - leq;  // exclusive prefix of (v==t)
  unsigned mybits = 0;
#pragma unroll
  for (int j = 0; j < 8; ++j) {
    int v = lv[j];
    bool kept = (v > t) || (v == t && eqp < need);
    if (v == t) eqp++;
    if (kept) mybits |= (1u << j);
  }
  atomicOr(&wbuf[tid >> 2], mybits << ((tid & 3) * 8));
  if (mybits) atomicMin(&sMin, base + __ffs(mybits) - 1);
  __syncthreads();
  if (tid < 64) keepw[(size_t)bh * 64 + tid] = wbuf[tid];
  if (tid == 0) jminb[bh] = sMin;
}

// ---------------- flash attention, 32x32 MFMA, lane-local softmax ----------------
// Wave = (bh, 32-row q-tile tau, key-part). S^T = mfma(K, Q): lane owns q = lane&31;
// its 16 S regs are k rows (reg&3)+8*(reg>>2)+4*hi. Softmax is lane-local (skip-rescale,
// per-q mrun). P -> PV A-frag via v_cvt_pk_bf16_f32 + v_permlane32_swap_b32 (no LDS).
// PV: O[32q][64d] = mfma(P_frag, V_frag) with V B-frags contiguous from vT.
// Split: tau>=32 and tau==0 -> 2 parts (partial m/l/O + combine); tau 1..31 direct.
#define PBLOAD(SUF, T)                                                         \
  do {                                                                         \
    const float* pb_ = pbrow + (T) * 32 + hi4;                                 \
    pbg0##SUF = *(const float4_t*)(pb_);                                       \
    pbg1##SUF = *(const float4_t*)(pb_ + 8);                                   \
    pbg2##SUF = *(const float4_t*)(pb_ + 16);                                  \
    pbg3##SUF = *(const float4_t*)(pb_ + 24);                                  \
    kw##SUF = kwp[T];                                                          \
  } while (0)

#define CHUNK32(SUF, OSUF, T)                                                  \
  do {                                                                         \
    int kb0c = (T) * 32;                                                       \
    const short* kp_ = kb_bh + (size_t)(kb0c + lq32) * DD + hi8;               \
    bf16x8 k0 = *(const bf16x8*)(kp_);                                         \
    bf16x8 k1 = *(const bf16x8*)(kp_ + 16);                                    \
    bf16x8 k2 = *(const bf16x8*)(kp_ + 32);                                    \
    bf16x8 k3 = *(const bf16x8*)(kp_ + 48);                                    \
    const short* vp0_ = vT0 + kb0c + hi8;                                      \
    const short* vp1_ = vT1 + kb0c + hi8;                                      \
    bf16x8 v00 = *(const bf16x8*)(vp0_);                                       \
    bf16x8 v01 = *(const bf16x8*)(vp0_ + 16);                                  \
    bf16x8 v10 = *(const bf16x8*)(vp1_);                                       \
    bf16x8 v11 = *(const bf16x8*)(vp1_ + 16);                                  \
    if ((T) + 1 < t1) PBLOAD(OSUF, (T) + 1);                                   \
    f32x16 s = Z16;                                                            \
    s = mfma32(k0, qf0, s);                                                    \
    s = mfma32(k1, qf1, s);                                                    \
    s = mfma32(k2, qf2, s);                                                    \
    s = mfma32(k3, qf3, s);                                                    \
    float sv[16];                                                              \
    unsigned vb = 0;                                                           \
    float cm = -FLT_MAX;                                                       \
    _Pragma("unroll") for (int g = 0; g < 4; ++g) {                            \
      float4_t pbg = (g == 0) ? pbg0##SUF : (g == 1) ? pbg1##SUF               \
                   : (g == 2) ? pbg2##SUF : pbg3##SUF;                         \
      _Pragma("unroll") for (int m = 0; m < 4; ++m) {                          \
        int rr = g * 4 + m;                                                    \
        int kk = m + g * 8 + hi4;                                              \
        int jj = kb0c + kk;                                                    \
        unsigned keep = (kw##SUF >> kk) & 1u;                                  \
        float x = (keep && jj <= qglob) ? fmaf(s[rr], 0.125f, pbg[m])          \
                                        : -FLT_MAX;                            \
        vb |= keep << rr;                                                      \
        sv[rr] = x;                                                            \
        cm = fmaxf(cm, x);                                                     \
      }                                                                        \
    }                                                                          \
    if (__any(cm > mrun)) {  /* rare: some row's max grew */                   \
      float rm = fmaxf(cm, __shfl_xor(cm, 32));                                \
      float mnew = fmaxf(mrun, rm);                                            \
      float fsc = __expf(mrun - mnew);                                         \
      mrun = mnew;                                                             \
      lsum *= fsc;                                                             \
      _Pragma("unroll") for (int rr = 0; rr < 16; ++rr) {                      \
        int qr = (rr & 3) + 8 * (rr >> 2) + hi4;                               \
        float fr = __shfl(fsc, qr);                                            \
        o0[rr] *= fr;                                                          \
        o1[rr] *= fr;                                                          \
      }                                                                        \
    }                                                                          \
    float pv[16];                                                              \
    float psum = 0.f;                                                          \
    _Pragma("unroll") for (int rr = 0; rr < 16; ++rr) {                        \
      float p_ = ((vb >> rr) & 1u) ? __expf(sv[rr] - mrun) : 0.f;              \
      pv[rr] = p_;                                                             \
      psum += p_;                                                              \
    }                                                                          \
    lsum += psum;                                                              \
    unsigned w0_, w1_, w2_, w3_, w4_, w5_, w6_, w7_;                           \
    asm("v_cvt_pk_bf16_f32 %0, %1, %2" : "=v"(w0_) : "v"(pv[0]), "v"(pv[1]));  \
    asm("v_cvt_pk_bf16_f32 %0, %1, %2" : "=v"(w1_) : "v"(pv[2]), "v"(pv[3]));  \
    asm("v_cvt_pk_bf16_f32 %0, %1, %2" : "=v"(w2_) : "v"(pv[4]), "v"(pv[5]));  \
    asm("v_cvt_pk_bf16_f32 %0, %1, %2" : "=v"(w3_) : "v"(pv[6]), "v"(pv[7]));  \
    asm("v_cvt_pk_bf16_f32 %0, %1, %2" : "=v"(w4_) : "v"(pv[8]), "v"(pv[9]));  \
    asm("v_cvt_pk_bf16_f32 %0, %1, %2" : "=v"(w5_) : "v"(pv[10]), "v"(pv[11]));\
    asm("v_cvt_pk_bf16_f32 %0, %1, %2" : "=v"(w6_) : "v"(pv[12]), "v"(pv[13]));\
    asm("v_cvt_pk_bf16_f32 %0, %1, %2" : "=v"(w7_) : "v"(pv[14]), "v"(pv[15]));\
    /* swap VDST.hi <-> VSRC.lo: frag words [X',X2',Y',Y2'] = k(0..7)+8hi */   \
    asm("v_permlane32_swap_b32 %0, %1" : "+v"(w0_), "+v"(w2_));                \
    asm("v_permlane32_swap_b32 %0, %1" : "+v"(w1_), "+v"(w3_));                \
    asm("v_permlane32_swap_b32 %0, %1" : "+v"(w4_), "+v"(w6_));                \
    asm("v_permlane32_swap_b32 %0, %1" : "+v"(w5_), "+v"(w7_));                \
    uint4_t u0_ = {w0_, w1_, w2_, w3_};                                        \
    uint4_t u1_ = {w4_, w5_, w6_, w7_};                                        \
    bf16x8 pf0 = __builtin_bit_cast(bf16x8, u0_);                              \
    bf16x8 pf1 = __builtin_bit_cast(bf16x8, u1_);                              \
    o0 = mfma32(pf0, v00, o0);                                                 \
    o0 = mfma32(pf1, v01, o0);                                                 \
    o1 = mfma32(pf0, v10, o1);                                                 \
    o1 = mfma32(pf1, v11, o1);                                                 \
  } while (0)

__global__ __launch_bounds__(128) void attn_split_kernel(
    const short* __restrict__ qb, const short* __restrict__ kb,
    const short* __restrict__ vT, const unsigned* __restrict__ keepw,
    const int* __restrict__ jminb, const float* __restrict__ pos_bias,
    short* __restrict__ Opart, float* __restrict__ mlb,
    short* __restrict__ attn_out) {
  int w = threadIdx.x >> 6, lane = threadIdx.x & 63;
  int lq32 = lane & 31, hi = lane >> 5;
  int hi4 = hi * 4, hi8 = hi * 8;
  int gid = blockIdx.x * 2 + w;      // 0..3103
  int bh = gid & 31;
  int r = gid >> 5;                  // 0..96, heavy-first rank
  int jmin = jminb[bh];

  int tau, part, t0, t1;
  bool big;
  if (r < 32) {                      // part0 of tau 63..32 (32 chunks)
    tau = 63 - r; part = 0; t0 = 0; t1 = 32; big = true;
  } else if (r < 34) {               // tau 0, 2 parts (64 chunks if degenerate)
    tau = 0; part = r - 32;
    int nkb = (jmin > 0) ? 64 : 1;
    int half = nkb >> 1;
    t0 = part ? half : 0;
    t1 = part ? nkb : half;
    big = true;
  } else if (r < 66) {               // part1 of tau 63..32 (32..1 chunks)
    tau = 63 - (r - 34); part = 1; t0 = 32; t1 = tau + 1; big = true;
  } else {                           // tau 31..1 single wave
    tau = 31 - (r - 66); part = 0; t0 = 0;
    t1 = (tau * 32 < jmin) ? 64 : tau + 1;   // degenerate rows need full range
    big = false;
  }
  int stile = (tau == 0) ? 32 : (tau - 32);
  int b = bh >> 4, h = bh & 15;
  int q0 = tau << 5;
  int qglob = q0 + lq32;

  const short* qp_ = qb + ((size_t)bh * NSEQ + qglob) * DD + hi8;
  bf16x8 qf0 = *(const bf16x8*)(qp_);
  bf16x8 qf1 = *(const bf16x8*)(qp_ + 16);
  bf16x8 qf2 = *(const bf16x8*)(qp_ + 32);
  bf16x8 qf3 = *(const bf16x8*)(qp_ + 48);

  const short* kb_bh = kb + (size_t)bh * NSEQ * DD;
  const short* vT0 = vT + ((size_t)bh * DD + lq32) * NSEQ;
  const short* vT1 = vT + ((size_t)bh * DD + 32 + lq32) * NSEQ;
  const float* pbrow = pos_bias + ((size_t)h * NSEQ + qglob) * NSEQ;
  const unsigned* kwp = keepw + (size_t)bh * 64;

  float mrun = -FLT_MAX, lsum = 0.f;
  f32x16 o0 = Z16, o1 = Z16;

  float4_t pbg0A, pbg1A, pbg2A, pbg3A, pbg0B, pbg1B, pbg2B, pbg3B;
  unsigned kwA, kwB;

  if (t0 < t1) {
    PBLOAD(A, t0);
    int t = t0;
    for (;;) {
      CHUNK32(A, B, t);
      if (++t >= t1) break;
      CHUNK32(B, A, t);
      if (++t >= t1) break;
    }
  }

  float ltot = lsum + __shfl_xor(lsum, 32);   // full row sum per q

  if (big) {
    int sidx = ((bh * 33 + stile) << 1) + part;
    if (hi == 0) {
      mlb[(size_t)sidx * 64 + lq32] = mrun;
      mlb[(size_t)sidx * 64 + 32 + lq32] = ltot;
    }
    short* op = Opart + (size_t)sidx * 2048;
#pragma unroll
    for (int rr = 0; rr < 16; ++rr) {
      int qr = (rr & 3) + 8 * (rr >> 2) + hi4;
      op[qr * 64 + lq32]      = f2bf(o0[rr]);
      op[qr * 64 + 32 + lq32] = f2bf(o1[rr]);
    }
  } else {
    float inv = 1.f / ltot;
    short* ob = attn_out + ((size_t)b * NSEQ + q0) * CDIM + h * DD + lq32;
#pragma unroll
    for (int rr = 0; rr < 16; ++rr) {
      int qr = (rr & 3) + 8 * (rr >> 2) + hi4;
      float ir = __shfl(inv, qr);
      short* orow = ob + (size_t)qr * CDIM;
      orow[0]  = f2bf(o0[rr] * ir);
      orow[32] = f2bf(o1[rr] * ir);
    }
  }
}

// ---------------- combine partials (tau 0 and tau 32..63) ----------------
__global__ __launch_bounds__(64) void combine_kernel(
    const float* __restrict__ mlb, const short* __restrict__ Opart,
    short* __restrict__ attn_out) {
  int blk = blockIdx.x;              // 0..1055
  int bh = blk & 31, st = blk >> 5;  // st 0..32
  int tau = (st < 32) ? (st + 32) : 0;
  int b = bh >> 4, h = bh & 15;
  int lane = threadIdx.x;
  int q = lane >> 1, d0 = (lane & 1) * 32;
  int p0 = (bh * 33 + st) << 1, p1 = p0 + 1;
  float m0 = mlb[(size_t)p0 * 64 + q], l0 = mlb[(size_t)p0 * 64 + 32 + q];
  float m1 = mlb[(size_t)p1 * 64 + q], l1 = mlb[(size_t)p1 * 64 + 32 + q];
  float M = fmaxf(m0, m1);
  float f0 = __expf(m0 - M), f1 = __expf(m1 - M);
  float L = l0 * f0 + l1 * f1;
  float inv = 1.f / L;
  const short* q0p = Opart + (size_t)p0 * 2048 + q * 64 + d0;
  const short* q1p = Opart + (size_t)p1 * 2048 + q * 64 + d0;
  short* orow = attn_out + ((size_t)b * NSEQ + tau * 32 + q) * CDIM + h * DD + d0;
#pragma unroll
  for (int c = 0; c < 4; ++c) {
    short8_t x0 = *(const short8_t*)(q0p + c * 8);
    short8_t x1 = *(const short8_t*)(q1p + c * 8);
    short8_t oo;
#pragma unroll
    for (int jj = 0; jj < 8; ++jj) {
      float a = bf2f(x0[jj]) * f0 + bf2f(x1[jj]) * f1;
      oo[jj] = f2bf(a * inv);
    }
    *(short8_t*)(orow + c * 8) = oo;
  }
}

// ---------------- launch ----------------
extern "C" void kernel_launch(void* const* d_in, const int* in_sizes, int n_in,
                              void* d_out, int out_size, void* d_ws, size_t ws_size,
                              hipStream_t stream) {
  const float* x        = (const float*)d_in[0];
  const float* Wqkv     = (const float*)d_in[1];
  const float* Wout     = (const float*)d_in[2];
  const float* pos_bias = (const float*)d_in[3];
  const int*   seq_mask = (const int*)d_in[4];
  float* out = (float*)d_out;

  char* ws = (char*)d_ws;
  short* qb    = (short*)(ws);                          // 0-8 MB   q bf16 [B,H,N,D]
  short* kbuf  = (short*)(ws + ((size_t)8  << 20));     // 8-16     k bf16 [B,H,N,D]
  short* vTb   = (short*)(ws + ((size_t)16 << 20));     // 16-24    vT bf16 [B,H,D,N]
  short* woutb = (short*)(ws + ((size_t)24 << 20));     // 24-26    W_out bf16
  short* xb    = (short*)(ws + ((size_t)26 << 20));     // 26-34    x bf16 (dead after GEMM0)
  short* aob   = (short*)(ws + ((size_t)26 << 20));     // 26-34    attn_out bf16 (overlay xb)
  short* wqkvb = (short*)(ws + ((size_t)34 << 20));     // 34-40    W_qkv bf16 (dead after GEMM0)
  short* Opart = (short*)(ws + ((size_t)34 << 20));     // 34-42.3  partials (overlay wqkvb)
  float* mlb   = (float*)(ws + ((size_t)43 << 20));     // 43-43.6  m/l per slot
  unsigned* keepw = (unsigned*)(ws + ((size_t)44 << 20)); // 44      keep bitmap [BH,64]
  int* jminb   = (int*)(ws + ((size_t)44 << 20) + 65536); // jmin [BH]

  cast_f32_bf16_kernel<<<4096, 256, 0, stream>>>(x, xb, (BB * NSEQ * CDIM) / 4);
  cast_wqkv_kernel<<<3072, 256, 0, stream>>>(Wqkv, wqkvb);
  cast_f32_bf16_kernel<<<1024, 256, 0, stream>>>(Wout, woutb, (CDIM * HH * DD) / 4);

  gemm_bt_kernel<0><<<dim3(24, 32), 256, 0, stream>>>(xb, wqkvb, CDIM, 3 * HH * DD,
                                                      nullptr, qb, kbuf, vTb);

  topk_kernel<<<BB * HH, 256, 0, stream>>>(seq_mask, keepw, jminb);

  attn_split_kernel<<<1552, 128, 0, stream>>>(qb, kbuf, vTb, keepw, jminb,
                                              pos_bias, Opart, mlb, aob);

  combine_kernel<<<1056, 64, 0, stream>>>(mlb, Opart, aob);

  gemm_bt_kernel<1><<<dim3(8, 32), 256, 0, stream>>>(aob, woutb, HH * DD, CDIM,
                                                     out, nullptr, nullptr, nullptr);
}